// Round 6
// baseline (254.171 us; speedup 1.0000x reference)
//
#include <hip/hip_runtime.h>

// MS Deformable Attention 3D — R9: head-partitioned XCD-pinned gather.
//  k_prep    : weights -> bf16 MFMA fragments
//  k_valproj : value @ W_val -> v_ws bf16 [b][h][pix][32]
//  k_attn_a  : GEMM1 + softmax + records -> global (gW 8B, gO 2B per sample)
//  k_gather  : blockIdx%8 == head -> each XCD reads ONE 1.7MB head slice (L2-fit)
//  k_out     : gathered bf16 @ W_out + b_out
// Falls back to the R6 fused kernel when ws_size < 75.7 MB.

#define EE   256
#define HH   8
#define LL   4
#define NQq  10000
#define BSB  2
#define LENV 13294
#define MQ   16
#define ROWS_V (BSB * LENV)   // 26588

// workspace layout (bytes):
//   wcat @ 0          : 393,216    (front guard for v_ws underreads >= -6464B)
//   v_ws @ 393,216    : 13,613,056
//   wval @ 14,006,272 : 131,072    (back guard for v_ws overreads <= ~6.5KB)
//   wout @ 14,137,344 : 131,072
//   gW   @ 14,268,416 : 40,960,000   (2*10000*256 uint2)
//   gO   @ 55,228,416 : 10,240,000   (2*10000*256 u16)
//   gOut @ 65,468,416 : 10,240,000   (2*10000*256 u16 bf16)
#define VWS_OFF  393216
#define GW_OFF   14268416
#define GO_OFF   55228416
#define GOUT_OFF 65468416
#define WS_NEED  75708416

typedef unsigned short u16;
typedef unsigned int   u32;
typedef __attribute__((ext_vector_type(8))) short bf16x8;
typedef __attribute__((ext_vector_type(4))) float f32x4;

__device__ __forceinline__ u32 bf16_of(float f) {
  u32 u = __float_as_uint(f);
  return (u + 0x7FFFu + ((u >> 16) & 1u)) >> 16;   // RNE
}
__device__ __forceinline__ float blo(u32 u) { return __uint_as_float(u << 16); }
__device__ __forceinline__ float bhi(u32 u) { return __uint_as_float(u & 0xFFFF0000u); }

__device__ __forceinline__ uint4 pack8(const float* f) {
  uint4 u;
  u.x = bf16_of(f[0]) | (bf16_of(f[1]) << 16);
  u.y = bf16_of(f[2]) | (bf16_of(f[3]) << 16);
  u.z = bf16_of(f[4]) | (bf16_of(f[5]) << 16);
  u.w = bf16_of(f[6]) | (bf16_of(f[7]) << 16);
  return u;
}

__device__ __forceinline__ void acc8(float o[8], uint4 q, float w) {
  o[0] += w * blo(q.x); o[1] += w * bhi(q.x);
  o[2] += w * blo(q.y); o[3] += w * bhi(q.y);
  o[4] += w * blo(q.z); o[5] += w * bhi(q.z);
  o[6] += w * blo(q.w); o[7] += w * bhi(q.w);
}

// ---- K0: weights -> bf16 B-fragment layout ----------------------------------
__global__ __launch_bounds__(64) void k_prep(
    const float* __restrict__ W_off, const float* __restrict__ W_attn,
    const float* __restrict__ W_val, const float* __restrict__ W_out,
    u16* __restrict__ wcat, u16* __restrict__ wval, u16* __restrict__ wout) {
  const int tile = blockIdx.x >> 3, s = blockIdx.x & 7;
  const int l = threadIdx.x, quad = l >> 4, r16 = l & 15;
  float f[8];
  u16* dst;
  if (tile < 48) {            // concat(W_off[256x512], W_attn[256x256])
    int col = tile * 16 + r16;
#pragma unroll
    for (int j = 0; j < 8; ++j) {
      int k = s * 32 + quad * 8 + j;
      f[j] = (col < 512) ? W_off[k * 512 + col] : W_attn[k * 256 + (col - 512)];
    }
    dst = wcat + ((tile * 8 + s) * 64 + l) * 8;
  } else if (tile < 64) {     // W_val[256x256]
    int col = (tile - 48) * 16 + r16;
#pragma unroll
    for (int j = 0; j < 8; ++j) f[j] = W_val[(s * 32 + quad * 8 + j) * 256 + col];
    dst = wval + (((tile - 48) * 8 + s) * 64 + l) * 8;
  } else {                    // W_out[256x256]
    int col = (tile - 64) * 16 + r16;
#pragma unroll
    for (int j = 0; j < 8; ++j) f[j] = W_out[(s * 32 + quad * 8 + j) * 256 + col];
    dst = wout + (((tile - 64) * 8 + s) * 64 + l) * 8;
  }
  *(uint4*)dst = pack8(f);
}

// ---- K1: value projection, MFMA, 64 rows/block, 512 threads / 8 waves -------
__global__ __launch_bounds__(512) void k_valproj(
    const float* __restrict__ value, const float* __restrict__ b_val,
    const u16* __restrict__ wval, u16* __restrict__ v_ws) {
  __shared__ __align__(16) u16 sA[64][264];
  const int tid = threadIdx.x;
  const int g0 = blockIdx.x * 64;
#pragma unroll
  for (int ch = 0; ch < 4; ++ch) {
    int fidx = ch * 4096 + tid * 8;
    int row = fidx >> 8, col = fidx & 255;
    int g = g0 + row;
    float fv[8] = {0.f, 0.f, 0.f, 0.f, 0.f, 0.f, 0.f, 0.f};
    if (g < ROWS_V) {
      float4 a = *(const float4*)(value + (long)g * 256 + col);
      float4 b = *(const float4*)(value + (long)g * 256 + col + 4);
      fv[0] = a.x; fv[1] = a.y; fv[2] = a.z; fv[3] = a.w;
      fv[4] = b.x; fv[5] = b.y; fv[6] = b.z; fv[7] = b.w;
    }
    *(uint4*)&sA[row][col] = pack8(fv);
  }
  __syncthreads();
  const int wave = tid >> 6, lane = tid & 63, quad = lane >> 4, r16 = lane & 15;
  f32x4 acc[2][4] = {};
  for (int s = 0; s < 8; ++s) {
    bf16x8 af[4];
#pragma unroll
    for (int mt = 0; mt < 4; ++mt)
      af[mt] = *(const bf16x8*)&sA[mt * 16 + r16][s * 32 + quad * 8];
#pragma unroll
    for (int nt = 0; nt < 2; ++nt) {
      int ntg = wave * 2 + nt;
      bf16x8 bfg = *(const bf16x8*)(wval + ((ntg * 8 + s) * 64 + lane) * 8);
#pragma unroll
      for (int mt = 0; mt < 4; ++mt)
        acc[nt][mt] = __builtin_amdgcn_mfma_f32_16x16x32_bf16(af[mt], bfg, acc[nt][mt], 0, 0, 0);
    }
  }
  __syncthreads();
#pragma unroll
  for (int nt = 0; nt < 2; ++nt) {
    int col = (wave * 2 + nt) * 16 + r16;
    float bias = b_val[col];
#pragma unroll
    for (int mt = 0; mt < 4; ++mt)
#pragma unroll
      for (int rr = 0; rr < 4; ++rr)
        sA[mt * 16 + quad * 4 + rr][col] = (u16)bf16_of(acc[nt][mt][rr] + bias);
  }
  __syncthreads();
#pragma unroll
  for (int it = 0; it < 4; ++it) {
    int chunk = it * 512 + tid;        // 0..2047
    int r  = chunk >> 5;               // row 0..63
    int hc = chunk & 31;               // head*4 + quarter
    int h2 = hc >> 2, qq = hc & 3;
    int g = g0 + r;
    if (g < ROWS_V) {
      int bb = g / LENV, pix = g - bb * LENV;
      *(uint4*)(v_ws + ((long)((bb * 8 + h2) * LENV + pix) * 32 + qq * 8)) =
          *(const uint4*)&sA[r][h2 * 32 + qq * 8];
    }
  }
}

// ---- K2a: GEMM1 + softmax + record build -> global records ------------------
__global__ __launch_bounds__(512, 6) void k_attn_a(
    const float* __restrict__ query, const float* __restrict__ query_pos,
    const float* __restrict__ refpts,
    const float* __restrict__ b_off, const float* __restrict__ b_attn,
    const u16* __restrict__ wcat,
    uint2* __restrict__ gW, u16* __restrict__ gO) {
  __shared__ __align__(16) char smem[49408];
  u16   (*sQ)[264] = (u16(*)[264])smem;     // staged q (bf16)
  float (*sC)[772] = (float(*)[772])smem;   // GEMM1 C (after sQ dead)

  const int tid = threadIdx.x;
  const int g0 = blockIdx.x * MQ;
  const int b = g0 / NQq;
  const int q0 = g0 - b * NQq;
  const int wave = tid >> 6, lane = tid & 63, quad = lane >> 4, r16 = lane & 15;

  // phase 0: stage q = query + query_pos as bf16
  {
    int fidx = tid * 8;
    int row = fidx >> 8, col = fidx & 255;
    long base = ((long)(b * NQq + q0 + row)) * 256 + col;
    float4 a0 = *(const float4*)(query + base);
    float4 a1 = *(const float4*)(query + base + 4);
    float4 p0 = *(const float4*)(query_pos + base);
    float4 p1 = *(const float4*)(query_pos + base + 4);
    float fv[8] = {a0.x + p0.x, a0.y + p0.y, a0.z + p0.z, a0.w + p0.w,
                   a1.x + p1.x, a1.y + p1.y, a1.z + p1.z, a1.w + p1.w};
    *(uint4*)&sQ[row][col] = pack8(fv);
  }
  __syncthreads();

  // phase 1: C[16][768] = q @ concat(W_off, W_attn)
  f32x4 acc[6] = {};
  for (int s = 0; s < 8; ++s) {
    bf16x8 af = *(const bf16x8*)&sQ[r16][s * 32 + quad * 8];
#pragma unroll
    for (int t6 = 0; t6 < 6; ++t6) {
      int tile = wave * 6 + t6;
      bf16x8 bfg = *(const bf16x8*)(wcat + ((tile * 8 + s) * 64 + lane) * 8);
      acc[t6] = __builtin_amdgcn_mfma_f32_16x16x32_bf16(af, bfg, acc[t6], 0, 0, 0);
    }
  }
  __syncthreads();                       // sQ dead
#pragma unroll
  for (int t6 = 0; t6 < 6; ++t6) {
    int col = (wave * 6 + t6) * 16 + r16;
#pragma unroll
    for (int rr = 0; rr < 4; ++rr)
      sC[quad * 4 + rr][col] = acc[t6][rr];
  }
  __syncthreads();

  // phase 2: softmax per (m, h) over 32 logits; thread = (m, h, g), g owns 8
  {
    const int m = tid >> 5, hh = (tid >> 2) & 7, g = tid & 3;
    float* p = &sC[m][512 + hh * 32 + g * 8];
    const float* ba = b_attn + hh * 32 + g * 8;
    float v[8];
    float mx = -1e30f;
#pragma unroll
    for (int j = 0; j < 8; ++j) { v[j] = p[j] + ba[j]; mx = fmaxf(mx, v[j]); }
    mx = fmaxf(mx, __shfl_xor(mx, 1));
    mx = fmaxf(mx, __shfl_xor(mx, 2));
    float sum = 0.f;
#pragma unroll
    for (int j = 0; j < 8; ++j) { v[j] = __expf(v[j] - mx); sum += v[j]; }
    sum += __shfl_xor(sum, 1);
    sum += __shfl_xor(sum, 2);
    float inv = 1.f / sum;
#pragma unroll
    for (int j = 0; j < 8; ++j) p[j] = v[j] * inv;
  }
  __syncthreads();

  // phase 3: build records -> global.
  //   gW = (w00|w01, w10|w11) bf16 pairs
  //   gO = (o00/64 + 128) bits 0..13 | dy_flag << 14   (dy stride is 0 or Wl)
  {
    const int s = tid & 255, mh = tid >> 8;
    const int l = (s >> 3) & 3;
    const int WlI[4] = {100, 50, 25, 13};
    const int baseI[4] = {0, 10000, 12500, 13125};
    const int Wl = WlI[l], Hl = WlI[l], base = baseI[l];
    const float WlF = (float)Wl;
    const float box = b_off[2 * s], boy = b_off[2 * s + 1];
    const long rb = ((long)(b * NQq + q0 + mh * 8)) * 256 + s;
#pragma unroll
    for (int mm = 0; mm < 8; ++mm) {
      int m = mh * 8 + mm;
      float w = sC[m][512 + s];
      float ax = sC[m][2 * s], ay = sC[m][2 * s + 1];
      float2 rp = *(const float2*)(refpts + (((long)(b * NQq + q0 + m)) * LL + l) * 2);
      float x = rp.x * WlF + (ax + box) - 0.5f;
      float y = rp.y * WlF + (ay + boy) - 0.5f;
      float fx0 = floorf(x), fy0 = floorf(y);
      int x0 = (int)fx0, y0 = (int)fy0;
      float fx = x - fx0, fy = y - fy0;
      bool xv0 = (x0 >= 0) & (x0 < Wl);
      bool xv1 = (x0 >= -1) & (x0 < Wl - 1);
      bool yv0 = (y0 >= 0) & (y0 < Hl);
      bool yv1 = (y0 >= -1) & (y0 < Hl - 1);
      float w00 = w * (1.f - fx) * (1.f - fy) * (float)(xv0 & yv0);
      float w01 = w * fx * (1.f - fy) * (float)(xv1 & yv0);
      float w10 = w * (1.f - fx) * fy * (float)(xv0 & yv1);
      float w11 = w * fx * fy * (float)(xv1 & yv1);
      int x0a = min(max(x0, -1), Wl - 1);
      int y0a = min(max(y0, -1), Hl - 1);
      int y1c = min(max(y0 + 1, 0), Hl - 1);
      int o00u = base + y0a * Wl + x0a;              // 64B units, [-101, 13293]
      int dyf  = y1c - y0a;                          // 0 or 1
      uint2 wr;
      wr.x = bf16_of(w00) | (bf16_of(w01) << 16);
      wr.y = bf16_of(w10) | (bf16_of(w11) << 16);
      gW[rb + mm * 256] = wr;
      gO[rb + mm * 256] = (u16)((o00u + 128) | (dyf << 14));
    }
  }
}

// ---- K2b: gather, blockIdx%8 == head -> XCD-local v_ws slice (1.7 MB) -------
__global__ __launch_bounds__(512, 6) void k_gather(
    const uint2* __restrict__ gW, const u16* __restrict__ gO,
    const char* __restrict__ wsb, u16* __restrict__ gOut) {
  const int h = blockIdx.x & 7;          // blockIdx%8 -> XCD pin
  const int t = blockIdx.x >> 3;
  const int b = t & 1;
  const int chunk = t >> 1;
  const int c4 = threadIdx.x & 3;
  const int ql = threadIdx.x >> 2;       // 0..127
  const int q = chunk * 128 + ql;
  if (q >= NQq) return;
  const long rbase = ((long)(b * NQq + q)) * 256 + h * 32;
  const u32 vbm = (u32)VWS_OFF + (u32)(b * 8 + h) * (u32)(LENV * 64)
                + (u32)c4 * 16u - 8192u;           // folds the +128 bias
  float oacc[8] = {};
#pragma unroll
  for (int g = 0; g < 4; ++g) {
    const u32 WL64 = (u32)(g == 0 ? 100 : g == 1 ? 50 : g == 2 ? 25 : 13) * 64u;
    const uint2* wp = gW + rbase + g * 8;
    uint4 wb0 = *(const uint4*)(wp);
    uint4 wb1 = *(const uint4*)(wp + 2);
    uint4 wb2 = *(const uint4*)(wp + 4);
    uint4 wb3 = *(const uint4*)(wp + 6);
    uint4 ob  = *(const uint4*)(gO + rbase + g * 8);
    u32 offs[8] = {ob.x & 0xFFFFu, ob.x >> 16, ob.y & 0xFFFFu, ob.y >> 16,
                   ob.z & 0xFFFFu, ob.z >> 16, ob.w & 0xFFFFu, ob.w >> 16};
    u32 wx[8] = {wb0.x, wb0.z, wb1.x, wb1.z, wb2.x, wb2.z, wb3.x, wb3.z};
    u32 wy[8] = {wb0.y, wb0.w, wb1.y, wb1.w, wb2.y, wb2.w, wb3.y, wb3.w};
#pragma unroll
    for (int j = 0; j < 8; ++j) {
      u32 o0 = vbm + ((offs[j] & 0x3FFFu) << 6);
      u32 o1 = o0 + (offs[j] >> 14) * WL64;
      uint4 q00 = *(const uint4*)(wsb + o0);
      uint4 q01 = *(const uint4*)(wsb + o0 + 64);
      uint4 q10 = *(const uint4*)(wsb + o1);
      uint4 q11 = *(const uint4*)(wsb + o1 + 64);
      acc8(oacc, q00, blo(wx[j]));
      acc8(oacc, q01, bhi(wx[j]));
      acc8(oacc, q10, blo(wy[j]));
      acc8(oacc, q11, bhi(wy[j]));
    }
  }
  *(uint4*)(gOut + rbase + c4 * 8) = pack8(oacc);
}

// ---- K2c: out = gathered @ W_out + b_out ------------------------------------
__global__ __launch_bounds__(512) void k_out(
    const u16* __restrict__ gOut, const u16* __restrict__ wout,
    const float* __restrict__ b_out, float* __restrict__ out) {
  __shared__ __align__(16) u16 sO[16][264];
  const int tid = threadIdx.x;
  const int g0 = blockIdx.x * MQ;
  const int b = g0 / NQq;
  const int q0 = g0 - b * NQq;
  const int wave = tid >> 6, lane = tid & 63, quad = lane >> 4, r16 = lane & 15;
  {
    int row = tid >> 5, col = (tid * 8) & 255;
    *(uint4*)&sO[row][col] =
        *(const uint4*)(gOut + ((long)(b * NQq + q0 + row)) * 256 + col);
  }
  __syncthreads();
  f32x4 acc2[2] = {};
  for (int s = 0; s < 8; ++s) {
    bf16x8 af = *(const bf16x8*)&sO[r16][s * 32 + quad * 8];
#pragma unroll
    for (int t2 = 0; t2 < 2; ++t2) {
      int tile = wave * 2 + t2;
      bf16x8 bfg = *(const bf16x8*)(wout + ((tile * 8 + s) * 64 + lane) * 8);
      acc2[t2] = __builtin_amdgcn_mfma_f32_16x16x32_bf16(af, bfg, acc2[t2], 0, 0, 0);
    }
  }
#pragma unroll
  for (int t2 = 0; t2 < 2; ++t2) {
    int col = (wave * 2 + t2) * 16 + r16;
    float bias = b_out[col];
#pragma unroll
    for (int rr = 0; rr < 4; ++rr) {
      int row = quad * 4 + rr;
      out[((long)(b * NQq + q0 + row)) * 256 + col] = acc2[t2][rr] + bias;
    }
  }
}

// ---- fallback: R6 fused k_attn (proven 123us) --------------------------------
__global__ __launch_bounds__(512, 6) void k_attn_fused(
    const float* __restrict__ query, const float* __restrict__ query_pos,
    const float* __restrict__ refpts,
    const float* __restrict__ b_off, const float* __restrict__ b_attn,
    const float* __restrict__ b_out,
    const u16* __restrict__ wcat, const u16* __restrict__ wout,
    const char* __restrict__ wsb, float* __restrict__ out) {
  __shared__ __align__(16) char smem[49408];
  u16   (*sQ)[264]   = (u16(*)[264])smem;
  float (*sC)[772]   = (float(*)[772])smem;
  uint2 (*sWgt)[256] = (uint2(*)[256])smem;
  u32   (*sOff)[256] = (u32(*)[256])(smem + 32768);
  u16   (*sO)[264]   = (u16(*)[264])smem;

  const int tid = threadIdx.x;
  const int g0 = blockIdx.x * MQ;
  const int b = g0 / NQq;
  const int q0 = g0 - b * NQq;
  const int wave = tid >> 6, lane = tid & 63, quad = lane >> 4, r16 = lane & 15;

  {
    int fidx = tid * 8;
    int row = fidx >> 8, col = fidx & 255;
    long base = ((long)(b * NQq + q0 + row)) * 256 + col;
    float4 a0 = *(const float4*)(query + base);
    float4 a1 = *(const float4*)(query + base + 4);
    float4 p0 = *(const float4*)(query_pos + base);
    float4 p1 = *(const float4*)(query_pos + base + 4);
    float fv[8] = {a0.x + p0.x, a0.y + p0.y, a0.z + p0.z, a0.w + p0.w,
                   a1.x + p1.x, a1.y + p1.y, a1.z + p1.z, a1.w + p1.w};
    *(uint4*)&sQ[row][col] = pack8(fv);
  }
  __syncthreads();

  f32x4 acc[6] = {};
  for (int s = 0; s < 8; ++s) {
    bf16x8 af = *(const bf16x8*)&sQ[r16][s * 32 + quad * 8];
#pragma unroll
    for (int t6 = 0; t6 < 6; ++t6) {
      int tile = wave * 6 + t6;
      bf16x8 bfg = *(const bf16x8*)(wcat + ((tile * 8 + s) * 64 + lane) * 8);
      acc[t6] = __builtin_amdgcn_mfma_f32_16x16x32_bf16(af, bfg, acc[t6], 0, 0, 0);
    }
  }
  __syncthreads();
#pragma unroll
  for (int t6 = 0; t6 < 6; ++t6) {
    int col = (wave * 6 + t6) * 16 + r16;
#pragma unroll
    for (int rr = 0; rr < 4; ++rr)
      sC[quad * 4 + rr][col] = acc[t6][rr];
  }
  __syncthreads();

  {
    const int m = tid >> 5, hh = (tid >> 2) & 7, g = tid & 3;
    float* p = &sC[m][512 + hh * 32 + g * 8];
    const float* ba = b_attn + hh * 32 + g * 8;
    float v[8];
    float mx = -1e30f;
#pragma unroll
    for (int j = 0; j < 8; ++j) { v[j] = p[j] + ba[j]; mx = fmaxf(mx, v[j]); }
    mx = fmaxf(mx, __shfl_xor(mx, 1));
    mx = fmaxf(mx, __shfl_xor(mx, 2));
    float sum = 0.f;
#pragma unroll
    for (int j = 0; j < 8; ++j) { v[j] = __expf(v[j] - mx); sum += v[j]; }
    sum += __shfl_xor(sum, 1);
    sum += __shfl_xor(sum, 2);
    float inv = 1.f / sum;
#pragma unroll
    for (int j = 0; j < 8; ++j) p[j] = v[j] * inv;
  }
  __syncthreads();

  uint2 wrecs[8];
  u32   orecs[8];
  {
    const int s = tid & 255, mh = tid >> 8;
    const int l = (s >> 3) & 3;
    const int WlI[4] = {100, 50, 25, 13};
    const int baseI[4] = {0, 10000, 12500, 13125};
    const int Wl = WlI[l], Hl = WlI[l], base = baseI[l];
    const float WlF = (float)Wl;
    const float box = b_off[2 * s], boy = b_off[2 * s + 1];
#pragma unroll
    for (int mm = 0; mm < 8; ++mm) {
      int m = mh * 8 + mm;
      float w = sC[m][512 + s];
      float ax = sC[m][2 * s], ay = sC[m][2 * s + 1];
      float2 rp = *(const float2*)(refpts + (((long)(b * NQq + q0 + m)) * LL + l) * 2);
      float x = rp.x * WlF + (ax + box) - 0.5f;
      float y = rp.y * WlF + (ay + boy) - 0.5f;
      float fx0 = floorf(x), fy0 = floorf(y);
      int x0 = (int)fx0, y0 = (int)fy0;
      float fx = x - fx0, fy = y - fy0;
      bool xv0 = (x0 >= 0) & (x0 < Wl);
      bool xv1 = (x0 >= -1) & (x0 < Wl - 1);
      bool yv0 = (y0 >= 0) & (y0 < Hl);
      bool yv1 = (y0 >= -1) & (y0 < Hl - 1);
      float w00 = w * (1.f - fx) * (1.f - fy) * (float)(xv0 & yv0);
      float w01 = w * fx * (1.f - fy) * (float)(xv1 & yv0);
      float w10 = w * (1.f - fx) * fy * (float)(xv0 & yv1);
      float w11 = w * fx * fy * (float)(xv1 & yv1);
      int x0a = min(max(x0, -1), Wl - 1);
      int y0a = min(max(y0, -1), Hl - 1);
      int y1c = min(max(y0 + 1, 0), Hl - 1);
      int o00u = base + y0a * Wl + x0a;
      u32 dyu  = (u32)((y1c - y0a) * Wl);
      wrecs[mm].x = bf16_of(w00) | (bf16_of(w01) << 16);
      wrecs[mm].y = bf16_of(w10) | (bf16_of(w11) << 16);
      orecs[mm]   = (u32)(o00u + 128) | (dyu << 14);
    }
  }
  __syncthreads();
  {
    const int s = tid & 255, mh = tid >> 8;
    const int jsw = (s & 224) | ((s + (s >> 5)) & 31);
#pragma unroll
    for (int mm = 0; mm < 8; ++mm) {
      sWgt[mh * 8 + mm][jsw] = wrecs[mm];
      sOff[mh * 8 + mm][jsw] = orecs[mm];
    }
  }
  __syncthreads();

  {
    const int c4 = tid & 3, hh = (tid >> 2) & 7, m = tid >> 5;
    const u32 vbm = (u32)VWS_OFF + (u32)(b * 8 + hh) * (u32)(LENV * 64)
                  + (u32)c4 * 16u - 8192u;
    float oacc[8] = {};
#pragma unroll 4
    for (int i = 0; i < 32; ++i) {
      const int srow = (hh << 5) | ((i + hh) & 31);
      uint2 wr = sWgt[m][srow];
      u32   po = sOff[m][srow];
      u32 off0 = vbm + ((po & 0x3FFFu) << 6);
      u32 off1 = off0 + ((po >> 14) << 6);
      uint4 q00 = *(const uint4*)(wsb + off0);
      uint4 q01 = *(const uint4*)(wsb + off0 + 64);
      uint4 q10 = *(const uint4*)(wsb + off1);
      uint4 q11 = *(const uint4*)(wsb + off1 + 64);
      acc8(oacc, q00, blo(wr.x));
      acc8(oacc, q01, bhi(wr.x));
      acc8(oacc, q10, blo(wr.y));
      acc8(oacc, q11, bhi(wr.y));
    }
    __syncthreads();
    *(uint4*)&sO[m][hh * 32 + c4 * 8] = pack8(oacc);
  }
  __syncthreads();

  f32x4 acc2[2] = {};
  for (int s = 0; s < 8; ++s) {
    bf16x8 af = *(const bf16x8*)&sO[r16][s * 32 + quad * 8];
#pragma unroll
    for (int t2 = 0; t2 < 2; ++t2) {
      int tile = wave * 2 + t2;
      bf16x8 bfg = *(const bf16x8*)(wout + ((tile * 8 + s) * 64 + lane) * 8);
      acc2[t2] = __builtin_amdgcn_mfma_f32_16x16x32_bf16(af, bfg, acc2[t2], 0, 0, 0);
    }
  }
#pragma unroll
  for (int t2 = 0; t2 < 2; ++t2) {
    int col = (wave * 2 + t2) * 16 + r16;
    float bias = b_out[col];
#pragma unroll
    for (int rr = 0; rr < 4; ++rr) {
      int row = quad * 4 + rr;
      out[((long)(b * NQq + q0 + row)) * 256 + col] = acc2[t2][rr] + bias;
    }
  }
}

extern "C" void kernel_launch(void* const* d_in, const int* in_sizes, int n_in,
                              void* d_out, int out_size, void* d_ws, size_t ws_size,
                              hipStream_t stream) {
  const float* query     = (const float*)d_in[0];
  const float* value     = (const float*)d_in[1];
  const float* query_pos = (const float*)d_in[2];
  const float* refpts    = (const float*)d_in[3];
  const float* W_off     = (const float*)d_in[5];
  const float* b_off     = (const float*)d_in[6];
  const float* W_attn    = (const float*)d_in[7];
  const float* b_attn    = (const float*)d_in[8];
  const float* W_val     = (const float*)d_in[9];
  const float* b_val     = (const float*)d_in[10];
  const float* W_out     = (const float*)d_in[11];
  const float* b_out     = (const float*)d_in[12];
  float* out = (float*)d_out;

  char* ws = (char*)d_ws;
  u16* wcat = (u16*)ws;
  u16* v_ws = (u16*)(ws + VWS_OFF);
  u16* wval = (u16*)(ws + VWS_OFF + 13613056);
  u16* wout = (u16*)(ws + VWS_OFF + 13613056 + 131072);

  k_prep<<<dim3(80 * 8), dim3(64), 0, stream>>>(W_off, W_attn, W_val, W_out,
                                                wcat, wval, wout);
  k_valproj<<<dim3((ROWS_V + 63) / 64), dim3(512), 0, stream>>>(value, b_val, wval, v_ws);

  if (ws_size >= (size_t)WS_NEED) {
    uint2* gW  = (uint2*)(ws + GW_OFF);
    u16*  gO   = (u16*)(ws + GO_OFF);
    u16*  gOut = (u16*)(ws + GOUT_OFF);
    k_attn_a<<<dim3(BSB * NQq / MQ), dim3(512), 0, stream>>>(
        query, query_pos, refpts, b_off, b_attn, wcat, gW, gO);
    k_gather<<<dim3(((NQq + 127) / 128) * BSB * HH), dim3(512), 0, stream>>>(
        gW, gO, ws, gOut);
    k_out<<<dim3(BSB * NQq / MQ), dim3(512), 0, stream>>>(gOut, wout, b_out, out);
  } else {
    k_attn_fused<<<dim3(BSB * NQq / MQ), dim3(512), 0, stream>>>(
        query, query_pos, refpts, b_off, b_attn, b_out, wcat, wout, ws, out);
  }
}

// Round 7
// 228.013 us; speedup vs baseline: 1.1147x; 1.1147x over previous
//
#include <hip/hip_runtime.h>

// MS Deformable Attention 3D — R10: fused kernel (split reverted) with
// pair-merged gather: 8 lanes per (m,h) read each y-pair as one contiguous
// 128B span (x0|x1 rows), 2 loads/sample instead of 4; m-swizzled record
// table columns; final shfl_xor(4) x-combine.

#define EE   256
#define HH   8
#define LL   4
#define NQq  10000
#define BSB  2
#define LENV 13294
#define MQ   16
#define ROWS_V (BSB * LENV)   // 26588

// workspace layout (bytes):
//   wcat  @ 0         : 393,216   (front guard for v_ws underreads >= -6464B)
//   v_ws  @ 393,216   : 13,613,056
//   wval  @ 14,006,272: 131,072   (back guard for v_ws overreads <= ~6.5KB)
//   wout  @ 14,137,344: 131,072
#define VWS_OFF 393216

typedef unsigned short u16;
typedef unsigned int   u32;
typedef __attribute__((ext_vector_type(8))) short bf16x8;
typedef __attribute__((ext_vector_type(4))) float f32x4;

__device__ __forceinline__ u32 bf16_of(float f) {
  u32 u = __float_as_uint(f);
  return (u + 0x7FFFu + ((u >> 16) & 1u)) >> 16;   // RNE
}
__device__ __forceinline__ float blo(u32 u) { return __uint_as_float(u << 16); }
__device__ __forceinline__ float bhi(u32 u) { return __uint_as_float(u & 0xFFFF0000u); }

__device__ __forceinline__ uint4 pack8(const float* f) {
  uint4 u;
  u.x = bf16_of(f[0]) | (bf16_of(f[1]) << 16);
  u.y = bf16_of(f[2]) | (bf16_of(f[3]) << 16);
  u.z = bf16_of(f[4]) | (bf16_of(f[5]) << 16);
  u.w = bf16_of(f[6]) | (bf16_of(f[7]) << 16);
  return u;
}

__device__ __forceinline__ void acc8(float o[8], uint4 q, float w) {
  o[0] += w * blo(q.x); o[1] += w * bhi(q.x);
  o[2] += w * blo(q.y); o[3] += w * bhi(q.y);
  o[4] += w * blo(q.z); o[5] += w * bhi(q.z);
  o[6] += w * blo(q.w); o[7] += w * bhi(q.w);
}

// ---- K0: weights -> bf16 B-fragment layout ----------------------------------
__global__ __launch_bounds__(64) void k_prep(
    const float* __restrict__ W_off, const float* __restrict__ W_attn,
    const float* __restrict__ W_val, const float* __restrict__ W_out,
    u16* __restrict__ wcat, u16* __restrict__ wval, u16* __restrict__ wout) {
  const int tile = blockIdx.x >> 3, s = blockIdx.x & 7;
  const int l = threadIdx.x, quad = l >> 4, r16 = l & 15;
  float f[8];
  u16* dst;
  if (tile < 48) {            // concat(W_off[256x512], W_attn[256x256])
    int col = tile * 16 + r16;
#pragma unroll
    for (int j = 0; j < 8; ++j) {
      int k = s * 32 + quad * 8 + j;
      f[j] = (col < 512) ? W_off[k * 512 + col] : W_attn[k * 256 + (col - 512)];
    }
    dst = wcat + ((tile * 8 + s) * 64 + l) * 8;
  } else if (tile < 64) {     // W_val[256x256]
    int col = (tile - 48) * 16 + r16;
#pragma unroll
    for (int j = 0; j < 8; ++j) f[j] = W_val[(s * 32 + quad * 8 + j) * 256 + col];
    dst = wval + (((tile - 48) * 8 + s) * 64 + l) * 8;
  } else {                    // W_out[256x256]
    int col = (tile - 64) * 16 + r16;
#pragma unroll
    for (int j = 0; j < 8; ++j) f[j] = W_out[(s * 32 + quad * 8 + j) * 256 + col];
    dst = wout + (((tile - 64) * 8 + s) * 64 + l) * 8;
  }
  *(uint4*)dst = pack8(f);
}

// ---- K1: value projection, MFMA, 64 rows/block, 512 threads / 8 waves -------
__global__ __launch_bounds__(512) void k_valproj(
    const float* __restrict__ value, const float* __restrict__ b_val,
    const u16* __restrict__ wval, u16* __restrict__ v_ws) {
  __shared__ __align__(16) u16 sA[64][264];
  const int tid = threadIdx.x;
  const int g0 = blockIdx.x * 64;
#pragma unroll
  for (int ch = 0; ch < 4; ++ch) {
    int fidx = ch * 4096 + tid * 8;
    int row = fidx >> 8, col = fidx & 255;
    int g = g0 + row;
    float fv[8] = {0.f, 0.f, 0.f, 0.f, 0.f, 0.f, 0.f, 0.f};
    if (g < ROWS_V) {
      float4 a = *(const float4*)(value + (long)g * 256 + col);
      float4 b = *(const float4*)(value + (long)g * 256 + col + 4);
      fv[0] = a.x; fv[1] = a.y; fv[2] = a.z; fv[3] = a.w;
      fv[4] = b.x; fv[5] = b.y; fv[6] = b.z; fv[7] = b.w;
    }
    *(uint4*)&sA[row][col] = pack8(fv);
  }
  __syncthreads();
  const int wave = tid >> 6, lane = tid & 63, quad = lane >> 4, r16 = lane & 15;
  f32x4 acc[2][4] = {};
  for (int s = 0; s < 8; ++s) {
    bf16x8 af[4];
#pragma unroll
    for (int mt = 0; mt < 4; ++mt)
      af[mt] = *(const bf16x8*)&sA[mt * 16 + r16][s * 32 + quad * 8];
#pragma unroll
    for (int nt = 0; nt < 2; ++nt) {
      int ntg = wave * 2 + nt;
      bf16x8 bfg = *(const bf16x8*)(wval + ((ntg * 8 + s) * 64 + lane) * 8);
#pragma unroll
      for (int mt = 0; mt < 4; ++mt)
        acc[nt][mt] = __builtin_amdgcn_mfma_f32_16x16x32_bf16(af[mt], bfg, acc[nt][mt], 0, 0, 0);
    }
  }
  __syncthreads();
#pragma unroll
  for (int nt = 0; nt < 2; ++nt) {
    int col = (wave * 2 + nt) * 16 + r16;
    float bias = b_val[col];
#pragma unroll
    for (int mt = 0; mt < 4; ++mt)
#pragma unroll
      for (int rr = 0; rr < 4; ++rr)
        sA[mt * 16 + quad * 4 + rr][col] = (u16)bf16_of(acc[nt][mt][rr] + bias);
  }
  __syncthreads();
#pragma unroll
  for (int it = 0; it < 4; ++it) {
    int chunk = it * 512 + tid;        // 0..2047
    int r  = chunk >> 5;               // row 0..63
    int hc = chunk & 31;               // head*4 + quarter
    int h2 = hc >> 2, qq = hc & 3;
    int g = g0 + r;
    if (g < ROWS_V) {
      int bb = g / LENV, pix = g - bb * LENV;
      *(uint4*)(v_ws + ((long)((bb * 8 + h2) * LENV + pix) * 32 + qq * 8)) =
          *(const uint4*)&sA[r][h2 * 32 + qq * 8];
    }
  }
}

// ---- K2: 16 queries/block, 512 threads ---------------------------------------
__global__ __launch_bounds__(512, 6) void k_attn(
    const float* __restrict__ query, const float* __restrict__ query_pos,
    const float* __restrict__ refpts,
    const float* __restrict__ b_off, const float* __restrict__ b_attn,
    const float* __restrict__ b_out,
    const u16* __restrict__ wcat, const u16* __restrict__ wout,
    const char* __restrict__ wsb, float* __restrict__ out) {
  __shared__ __align__(16) char smem[49408];
  u16   (*sQ)[264]   = (u16(*)[264])smem;          // staged q (bf16)
  float (*sC)[772]   = (float(*)[772])smem;        // GEMM1 C (after sQ dead)
  uint2 (*sWgt)[256] = (uint2(*)[256])smem;        // record weights (after sC dead)
  u32   (*sOff)[256] = (u32(*)[256])(smem + 32768);// packed o00|dy
  u16   (*sO)[264]   = (u16(*)[264])smem;          // gather output (after tables dead)

  const int tid = threadIdx.x;
  const int g0 = blockIdx.x * MQ;
  const int b = g0 / NQq;
  const int q0 = g0 - b * NQq;
  const int wave = tid >> 6, lane = tid & 63, quad = lane >> 4, r16 = lane & 15;

  // phase 0: stage q = query + query_pos as bf16
  {
    int fidx = tid * 8;
    int row = fidx >> 8, col = fidx & 255;
    long base = ((long)(b * NQq + q0 + row)) * 256 + col;
    float4 a0 = *(const float4*)(query + base);
    float4 a1 = *(const float4*)(query + base + 4);
    float4 p0 = *(const float4*)(query_pos + base);
    float4 p1 = *(const float4*)(query_pos + base + 4);
    float fv[8] = {a0.x + p0.x, a0.y + p0.y, a0.z + p0.z, a0.w + p0.w,
                   a1.x + p1.x, a1.y + p1.y, a1.z + p1.z, a1.w + p1.w};
    *(uint4*)&sQ[row][col] = pack8(fv);
  }
  __syncthreads();

  // phase 1: C[16][768] = q @ concat(W_off, W_attn)   (48 n-tiles / 8 waves)
  f32x4 acc[6] = {};
  for (int s = 0; s < 8; ++s) {
    bf16x8 af = *(const bf16x8*)&sQ[r16][s * 32 + quad * 8];
#pragma unroll
    for (int t6 = 0; t6 < 6; ++t6) {
      int tile = wave * 6 + t6;
      bf16x8 bfg = *(const bf16x8*)(wcat + ((tile * 8 + s) * 64 + lane) * 8);
      acc[t6] = __builtin_amdgcn_mfma_f32_16x16x32_bf16(af, bfg, acc[t6], 0, 0, 0);
    }
  }
  __syncthreads();                       // sQ dead
#pragma unroll
  for (int t6 = 0; t6 < 6; ++t6) {
    int col = (wave * 6 + t6) * 16 + r16;
#pragma unroll
    for (int rr = 0; rr < 4; ++rr)
      sC[quad * 4 + rr][col] = acc[t6][rr];
  }
  __syncthreads();

  // phase 2: softmax per (m, h) over 32 logits; thread = (m, h, g), g owns 8
  {
    const int m = tid >> 5, hh = (tid >> 2) & 7, g = tid & 3;
    float* p = &sC[m][512 + hh * 32 + g * 8];
    const float* ba = b_attn + hh * 32 + g * 8;
    float v[8];
    float mx = -1e30f;
#pragma unroll
    for (int j = 0; j < 8; ++j) { v[j] = p[j] + ba[j]; mx = fmaxf(mx, v[j]); }
    mx = fmaxf(mx, __shfl_xor(mx, 1));
    mx = fmaxf(mx, __shfl_xor(mx, 2));
    float sum = 0.f;
#pragma unroll
    for (int j = 0; j < 8; ++j) { v[j] = __expf(v[j] - mx); sum += v[j]; }
    sum += __shfl_xor(sum, 1);
    sum += __shfl_xor(sum, 2);
    float inv = 1.f / sum;
#pragma unroll
    for (int j = 0; j < 8; ++j) p[j] = v[j] * inv;
  }
  __syncthreads();

  // phase 3: build packed records.
  //   wgt = (w00|w01, w10|w11) bf16 pairs
  //   off = (o00/64 + 128) bits 0..13  |  (dy/64) << 14   (dy/64 <= 100)
  // o00 byte offset of corner00, x/y clamped to [-1, Wl-1]; x+1 corner = +64B.
  // Invalid corners have weight 0; guard reads land in wcat/wval around v_ws.
  // Table column swizzle: col(s,m) = (s & 224) | ((s + m) & 31) — spreads the
  // gather's per-m broadcast reads (wave-uniform s) across 16 distinct banks.
  uint2 wrecs[8];
  u32   orecs[8];
  {
    const int s = tid & 255, mh = tid >> 8;
    const int l = (s >> 3) & 3;
    const int WlI[4] = {100, 50, 25, 13};
    const int baseI[4] = {0, 10000, 12500, 13125};
    const int Wl = WlI[l], Hl = WlI[l], base = baseI[l];
    const float WlF = (float)Wl;
    const float box = b_off[2 * s], boy = b_off[2 * s + 1];
#pragma unroll
    for (int mm = 0; mm < 8; ++mm) {
      int m = mh * 8 + mm;
      float w = sC[m][512 + s];
      float ax = sC[m][2 * s], ay = sC[m][2 * s + 1];
      float2 rp = *(const float2*)(refpts + (((long)(b * NQq + q0 + m)) * LL + l) * 2);
      float x = rp.x * WlF + (ax + box) - 0.5f;
      float y = rp.y * WlF + (ay + boy) - 0.5f;
      float fx0 = floorf(x), fy0 = floorf(y);
      int x0 = (int)fx0, y0 = (int)fy0;
      float fx = x - fx0, fy = y - fy0;
      bool xv0 = (x0 >= 0) & (x0 < Wl);
      bool xv1 = (x0 >= -1) & (x0 < Wl - 1);
      bool yv0 = (y0 >= 0) & (y0 < Hl);
      bool yv1 = (y0 >= -1) & (y0 < Hl - 1);
      float w00 = w * (1.f - fx) * (1.f - fy) * (float)(xv0 & yv0);
      float w01 = w * fx * (1.f - fy) * (float)(xv1 & yv0);
      float w10 = w * (1.f - fx) * fy * (float)(xv0 & yv1);
      float w11 = w * fx * fy * (float)(xv1 & yv1);
      int x0a = min(max(x0, -1), Wl - 1);
      int y0a = min(max(y0, -1), Hl - 1);
      int y1c = min(max(y0 + 1, 0), Hl - 1);
      int o00u = base + y0a * Wl + x0a;              // 64B units, [-101, 13293]
      u32 dyu  = (u32)((y1c - y0a) * Wl);            // 64B units, 0..100
      wrecs[mm].x = bf16_of(w00) | (bf16_of(w01) << 16);
      wrecs[mm].y = bf16_of(w10) | (bf16_of(w11) << 16);
      orecs[mm]   = (u32)(o00u + 128) | (dyu << 14);
    }
  }
  __syncthreads();                       // sC dead
  {
    const int s = tid & 255, mh = tid >> 8;
#pragma unroll
    for (int mm = 0; mm < 8; ++mm) {
      int m = mh * 8 + mm;
      int col = (s & 224) | ((s + m) & 31);
      sWgt[m][col] = wrecs[mm];
      sOff[m][col] = orecs[mm];
    }
  }
  __syncthreads();

  // phase 4: pair-merged gather. 8 lanes per (m,h) group; each group handles
  // m0 and m0+8. Lanes 0-3 read the x0 row, lanes 4-7 the x1 row (+64B) —
  // each y-pair is ONE contiguous 128B span. x-combine via shfl_xor(4).
  {
    const int c8 = tid & 7, g8 = tid >> 3;
    const int m0 = g8 & 7, hh = g8 >> 3;
    const int xsel = c8 >> 2;            // 0: x0 corner, 1: x1 corner
    const int sb = hh << 5;
    const u32 vbm = (u32)VWS_OFF + (u32)(b * 8 + hh) * (u32)(LENV * 64)
                  + (u32)(c8 & 3) * 16u + (u32)xsel * 64u - 8192u;
    float oa[8] = {}, ob[8] = {};
#pragma unroll 4
    for (int i = 0; i < 32; ++i) {
      const int colA = sb | ((i + m0) & 31);
      const int colB = sb | ((i + m0 + 8) & 31);
      uint2 wrA = sWgt[m0][colA];
      u32   poA = sOff[m0][colA];
      uint2 wrB = sWgt[m0 + 8][colB];
      u32   poB = sOff[m0 + 8][colB];
      u32 a0 = vbm + ((poA & 0x3FFFu) << 6);
      u32 a1 = a0 + ((poA >> 14) << 6);
      u32 b0 = vbm + ((poB & 0x3FFFu) << 6);
      u32 b1 = b0 + ((poB >> 14) << 6);
      uint4 qa0 = *(const uint4*)(wsb + a0);
      uint4 qa1 = *(const uint4*)(wsb + a1);
      uint4 qb0 = *(const uint4*)(wsb + b0);
      uint4 qb1 = *(const uint4*)(wsb + b1);
      float wA0 = xsel ? bhi(wrA.x) : blo(wrA.x);  // w01 : w00
      float wA1 = xsel ? bhi(wrA.y) : blo(wrA.y);  // w11 : w10
      float wB0 = xsel ? bhi(wrB.x) : blo(wrB.x);
      float wB1 = xsel ? bhi(wrB.y) : blo(wrB.y);
      acc8(oa, qa0, wA0);
      acc8(oa, qa1, wA1);
      acc8(ob, qb0, wB0);
      acc8(ob, qb1, wB1);
    }
#pragma unroll
    for (int j = 0; j < 8; ++j) {
      oa[j] += __shfl_xor(oa[j], 4);
      ob[j] += __shfl_xor(ob[j], 4);
    }
    __syncthreads();                     // tables dead
    if (!xsel) {
      *(uint4*)&sO[m0][hh * 32 + c8 * 8]     = pack8(oa);
      *(uint4*)&sO[m0 + 8][hh * 32 + c8 * 8] = pack8(ob);
    }
  }
  __syncthreads();

  // phase 5: out = gathered @ W_out + b_out  (16 n-tiles / 8 waves)
  f32x4 acc2[2] = {};
  for (int s = 0; s < 8; ++s) {
    bf16x8 af = *(const bf16x8*)&sO[r16][s * 32 + quad * 8];
#pragma unroll
    for (int t2 = 0; t2 < 2; ++t2) {
      int tile = wave * 2 + t2;
      bf16x8 bfg = *(const bf16x8*)(wout + ((tile * 8 + s) * 64 + lane) * 8);
      acc2[t2] = __builtin_amdgcn_mfma_f32_16x16x32_bf16(af, bfg, acc2[t2], 0, 0, 0);
    }
  }
#pragma unroll
  for (int t2 = 0; t2 < 2; ++t2) {
    int col = (wave * 2 + t2) * 16 + r16;
    float bias = b_out[col];
#pragma unroll
    for (int rr = 0; rr < 4; ++rr) {
      int row = quad * 4 + rr;
      out[((long)(b * NQq + q0 + row)) * 256 + col] = acc2[t2][rr] + bias;
    }
  }
}

extern "C" void kernel_launch(void* const* d_in, const int* in_sizes, int n_in,
                              void* d_out, int out_size, void* d_ws, size_t ws_size,
                              hipStream_t stream) {
  const float* query     = (const float*)d_in[0];
  const float* value     = (const float*)d_in[1];
  const float* query_pos = (const float*)d_in[2];
  const float* refpts    = (const float*)d_in[3];
  const float* W_off     = (const float*)d_in[5];
  const float* b_off     = (const float*)d_in[6];
  const float* W_attn    = (const float*)d_in[7];
  const float* b_attn    = (const float*)d_in[8];
  const float* W_val     = (const float*)d_in[9];
  const float* b_val     = (const float*)d_in[10];
  const float* W_out     = (const float*)d_in[11];
  const float* b_out     = (const float*)d_in[12];
  float* out = (float*)d_out;

  char* ws = (char*)d_ws;
  u16* wcat = (u16*)ws;                                   //    393,216 B @ 0
  u16* v_ws = (u16*)(ws + VWS_OFF);                       // 13,613,056 B
  u16* wval = (u16*)(ws + VWS_OFF + 13613056);            //    131,072 B
  u16* wout = (u16*)(ws + VWS_OFF + 13613056 + 131072);   //    131,072 B

  k_prep<<<dim3(80 * 8), dim3(64), 0, stream>>>(W_off, W_attn, W_val, W_out,
                                                wcat, wval, wout);
  k_valproj<<<dim3((ROWS_V + 63) / 64), dim3(512), 0, stream>>>(value, b_val, wval, v_ws);
  k_attn<<<dim3(BSB * NQq / MQ), dim3(512), 0, stream>>>(
      query, query_pos, refpts, b_off, b_attn, b_out, wcat, wout, ws, out);
}